// Round 3
// baseline (277.845 us; speedup 1.0000x reference)
//
#include <hip/hip_runtime.h>
#include <hip/hip_bf16.h>

#define NB 16
#define NL 8192
#define ND 256

#define KSPLIT 32
#define BK 64
#define KSTRIDE 72   // bf16 elems per LDS column; 144 B -> 16B aligned

// ws layout (floats): [0,16) Z[b]; [256, 256+NB*NL) s_l; [131328, +KSPLIT*3*NB*16384) gram partials
#define WS_S_OFF 256
#define WS_G_OFF 131328

typedef __bf16 bf16_t;
typedef __attribute__((ext_vector_type(8))) __bf16 bf16x8;
typedef __attribute__((ext_vector_type(4))) float floatx4;

// K1: one row per wave. 64 lanes x float4 = full 256-col row. Writes
// s_l = exp(norm/2) and per-block partial Z = sum(e_l) (e = s*s).
__global__ __launch_bounds__(256) void k_norm_exp(const float* __restrict__ x,
                                                  float* __restrict__ ws) {
    const int t = threadIdx.x;
    const int lane = t & 63;
    const int wave = t >> 6;
    const int row0 = blockIdx.x * 32 + wave * 8;
    const int b = blockIdx.x >> 8;          // 256 blocks per batch
    float* s_out = ws + WS_S_OFF;
    float e_acc = 0.f;
    #pragma unroll
    for (int i = 0; i < 8; ++i) {
        const int r = row0 + i;
        float4 v = *(const float4*)(x + (size_t)r * ND + lane * 4);
        float ss = v.x * v.x + v.y * v.y + v.z * v.z + v.w * v.w;
        #pragma unroll
        for (int off = 32; off; off >>= 1) ss += __shfl_xor(ss, off, 64);
        const float s = __expf(0.5f * sqrtf(ss));
        if (lane == 0) s_out[r] = s;
        e_acc += s * s;
    }
    __shared__ float red[4];
    if (lane == 0) red[wave] = e_acc;
    __syncthreads();
    if (t == 0) atomicAdd(&ws[b], red[0] + red[1] + red[2] + red[3]);
}

// K3: per batch, partial Gram of Y = diag(s) X over a k-chunk, bf16 MFMA.
// blockIdx: x = k-chunk, y = quadrant tp {0:(0,0), 1:(0,1), 2:(1,1)}, z = batch.
// Partial 128x128 written (plain stores) to ws.
__global__ __launch_bounds__(256, 4) void k_gemm(const float* __restrict__ x,
                                                 const float* __restrict__ ws,
                                                 float* __restrict__ gram) {
    const int ks = blockIdx.x;
    const int tp = blockIdx.y;
    const int b  = blockIdx.z;
    const int t = threadIdx.x;
    const int wave = t >> 6, lane = t & 63;

    const int C       = (tp == 1) ? 256 : 128;  // staged cols
    const int col_off = (tp == 2) ? 128 : 0;    // global col of LDS col 0
    const int cshift  = (tp == 1) ? 6 : 5;      // log2(C/4)
    const int cmask   = (C >> 2) - 1;
    const int nunits  = C >> 7;                 // 1 or 2
    const int bcol    = (tp == 1) ? 128 : 0;    // B-operand base col in LDS

    __shared__ bf16_t lds[256 * KSTRIDE];       // [col][k], transposed tile

    const float* xb = x + (size_t)b * NL * ND;
    const float* sb = ws + WS_S_OFF + b * NL;
    const int l0 = ks * (NL / KSPLIT);

    floatx4 acc[2][8];
    #pragma unroll
    for (int rt = 0; rt < 2; ++rt)
        #pragma unroll
        for (int ct = 0; ct < 8; ++ct)
            #pragma unroll
            for (int r = 0; r < 4; ++r) acc[rt][ct][r] = 0.f;

    for (int kk = 0; kk < NL / KSPLIT; kk += BK) {
        __syncthreads();
        // stage: unit = 4 cols x 8 k's: 8 float4 loads (16B/lane coalesced),
        // scale by s, pack transposed, 4x ds_write_b128.
        for (int i = 0; i < nunits; ++i) {
            const int u  = t + i * 256;
            const int cg = u & cmask;
            const int kg = u >> cshift;         // 0..7
            const int lrow = l0 + kk + kg * 8;
            const float* gp = xb + (size_t)lrow * ND + col_off + cg * 4;
            bf16x8 p[4];
            {
                float4 v[4]; float sc[4];
                #pragma unroll
                for (int j = 0; j < 4; ++j) { v[j] = *(const float4*)(gp + j * ND); sc[j] = sb[lrow + j]; }
                #pragma unroll
                for (int c = 0; c < 4; ++c) {
                    const float* vf;
                    #pragma unroll
                    for (int j = 0; j < 4; ++j) { vf = (const float*)&v[j]; p[c][j] = (bf16_t)(vf[c] * sc[j]); }
                }
            }
            {
                float4 v[4]; float sc[4];
                #pragma unroll
                for (int j = 0; j < 4; ++j) { v[j] = *(const float4*)(gp + (j + 4) * ND); sc[j] = sb[lrow + 4 + j]; }
                #pragma unroll
                for (int c = 0; c < 4; ++c) {
                    const float* vf;
                    #pragma unroll
                    for (int j = 0; j < 4; ++j) { vf = (const float*)&v[j]; p[c][4 + j] = (bf16_t)(vf[c] * sc[j]); }
                }
            }
            #pragma unroll
            for (int c = 0; c < 4; ++c)
                *(bf16x8*)(lds + (4 * cg + c) * KSTRIDE + kg * 8) = p[c];
        }
        __syncthreads();
        #pragma unroll
        for (int k2 = 0; k2 < 2; ++k2) {
            const int koff = k2 * 32 + (lane >> 4) * 8;
            bf16x8 af[2], bfr[8];
            #pragma unroll
            for (int rt = 0; rt < 2; ++rt) {
                const int col = (wave * 2 + rt) * 16 + (lane & 15);
                af[rt] = *(const bf16x8*)(lds + col * KSTRIDE + koff);
            }
            #pragma unroll
            for (int ct = 0; ct < 8; ++ct) {
                const int col = bcol + ct * 16 + (lane & 15);
                bfr[ct] = *(const bf16x8*)(lds + col * KSTRIDE + koff);
            }
            #pragma unroll
            for (int rt = 0; rt < 2; ++rt)
                #pragma unroll
                for (int ct = 0; ct < 8; ++ct)
                    acc[rt][ct] = __builtin_amdgcn_mfma_f32_16x16x32_bf16(
                        af[rt], bfr[ct], acc[rt][ct], 0, 0, 0);
        }
    }

    // epilogue: plain stores of the 128x128 partial (C/D: col=lane&15, row=(lane>>4)*4+reg)
    float* wq = gram + (size_t)((ks * 3 + tp) * 16 + b) * 16384;
    #pragma unroll
    for (int rt = 0; rt < 2; ++rt) {
        const int d0 = (wave * 2 + rt) * 16 + (lane >> 4) * 4;
        #pragma unroll
        for (int ct = 0; ct < 8; ++ct) {
            const int e = ct * 16 + (lane & 15);
            #pragma unroll
            for (int reg = 0; reg < 4; ++reg)
                wq[(size_t)(d0 + reg) * 128 + e] = acc[rt][ct][reg];
        }
    }
}

// K4: sum KSPLIT partials, scale by 1/Z, scatter 3 quadrants to out.
__global__ __launch_bounds__(256) void k_reduce(const float* __restrict__ gram,
                                                const float* __restrict__ ws,
                                                float* __restrict__ out) {
    const int gid = blockIdx.x * 256 + threadIdx.x;
    const int idx = gid & 16383;
    const int q   = gid >> 14;        // 0..47
    const int tp  = q / 16;
    const int b   = q % 16;
    const float rz = 1.0f / ws[b];
    float sum = 0.f;
    #pragma unroll
    for (int ks = 0; ks < KSPLIT; ++ks)
        sum += gram[(size_t)((ks * 3 + tp) * 16 + b) * 16384 + idx];
    sum *= rz;
    const int d = idx >> 7, e = idx & 127;
    float* ob = out + (size_t)b * ND * ND;
    if (tp == 0)      ob[(size_t)d * ND + e] = sum;
    else if (tp == 1) ob[(size_t)d * ND + 128 + e] = sum;
    else              ob[(size_t)(128 + d) * ND + 128 + e] = sum;
}

// K5: out[b, 128:, :128] = out[b, :128, 128:]^T via LDS 32x32 tiles.
__global__ __launch_bounds__(256) void k_mirror(float* __restrict__ out) {
    __shared__ float tile[32][33];
    const int tx = threadIdx.x & 31, ty = threadIdx.x >> 5;   // 32x8
    const int x0 = blockIdx.x * 32;   // d
    const int y0 = blockIdx.y * 32;   // e-local
    float* ob = out + (size_t)blockIdx.z * ND * ND;
    #pragma unroll
    for (int p = 0; p < 4; ++p)
        tile[ty + 8 * p][tx] = ob[(size_t)(x0 + ty + 8 * p) * ND + 128 + y0 + tx];
    __syncthreads();
    #pragma unroll
    for (int p = 0; p < 4; ++p)
        ob[(size_t)(128 + y0 + ty + 8 * p) * ND + x0 + tx] = tile[tx][ty + 8 * p];
}

extern "C" void kernel_launch(void* const* d_in, const int* in_sizes, int n_in,
                              void* d_out, int out_size, void* d_ws, size_t ws_size,
                              hipStream_t stream) {
    const float* x = (const float*)d_in[0];
    float* out = (float*)d_out;
    float* ws = (float*)d_ws;
    float* gram = ws + WS_G_OFF;

    hipMemsetAsync(d_ws, 0, 64, stream);  // zero Z[16]
    k_norm_exp<<<dim3(NB * NL / 32), 256, 0, stream>>>(x, ws);
    k_gemm<<<dim3(KSPLIT, 3, NB), 256, 0, stream>>>(x, ws, gram);
    k_reduce<<<dim3(3 * NB * 16384 / 256), 256, 0, stream>>>(gram, ws, out);
    k_mirror<<<dim3(4, 4, NB), 256, 0, stream>>>(out);
}

// Round 4
// 258.919 us; speedup vs baseline: 1.0731x; 1.0731x over previous
//
#include <hip/hip_runtime.h>
#include <hip/hip_bf16.h>

#define NB 16
#define NL 8192
#define ND 256

#define KSPLIT 32
#define BK 64
#define KSTRIDE 72   // bf16 elems per LDS column; 144 B -> 16B aligned

// ws layout (floats): [0,16) rz[b]=1/Z; [256, 256+NB*NL) s_l; [131328, ...) gram partials
#define WS_S_OFF 256
#define WS_G_OFF 131328

typedef __bf16 bf16_t;
typedef __attribute__((ext_vector_type(8))) __bf16 bf16x8;
typedef __attribute__((ext_vector_type(4))) float floatx4;

// K1: one row per wave, 16 rows unrolled -> 16 independent 1KB wave-loads in
// flight. Writes s_l = exp(norm/2) only. No LDS, no atomics, no barriers.
__global__ __launch_bounds__(256) void k_norm_exp(const float* __restrict__ x,
                                                  float* __restrict__ ws) {
    const int t = threadIdx.x;
    const int lane = t & 63;
    const int wave = t >> 6;
    const int row0 = blockIdx.x * 64 + wave * 16;
    float* s_out = ws + WS_S_OFF;
    float4 v[16];
    #pragma unroll
    for (int i = 0; i < 16; ++i)
        v[i] = *(const float4*)(x + (size_t)(row0 + i) * ND + lane * 4);
    #pragma unroll
    for (int i = 0; i < 16; ++i) {
        float ss = v[i].x * v[i].x + v[i].y * v[i].y + v[i].z * v[i].z + v[i].w * v[i].w;
        #pragma unroll
        for (int off = 32; off; off >>= 1) ss += __shfl_xor(ss, off, 64);
        if (lane == 0) s_out[row0 + i] = __expf(0.5f * sqrtf(ss));
    }
}

// K2: per batch: ws[b] = 1 / sum(s^2). 16 blocks, reads s from L2/L3.
__global__ __launch_bounds__(256) void k_zsum(float* __restrict__ ws) {
    const int b = blockIdx.x;
    const float* sb = ws + WS_S_OFF + b * NL;
    const int t = threadIdx.x;
    float sum = 0.f;
    #pragma unroll
    for (int i = 0; i < 32; ++i) { const float s = sb[t + i * 256]; sum += s * s; }
    #pragma unroll
    for (int off = 32; off; off >>= 1) sum += __shfl_xor(sum, off, 64);
    __shared__ float red[4];
    if ((t & 63) == 0) red[t >> 6] = sum;
    __syncthreads();
    if (t == 0) ws[b] = 1.0f / (red[0] + red[1] + red[2] + red[3]);
}

// K3: per batch, partial Gram of Y = diag(s) X over a k-chunk, bf16 MFMA.
// blockIdx: x = k-chunk, y = quadrant tp {0:(0,0), 1:(0,1), 2:(1,1)}, z = batch.
__global__ __launch_bounds__(256, 4) void k_gemm(const float* __restrict__ x,
                                                 const float* __restrict__ ws,
                                                 float* __restrict__ gram) {
    const int ks = blockIdx.x;
    const int tp = blockIdx.y;
    const int b  = blockIdx.z;
    const int t = threadIdx.x;
    const int wave = t >> 6, lane = t & 63;

    const int C       = (tp == 1) ? 256 : 128;  // staged cols
    const int col_off = (tp == 2) ? 128 : 0;    // global col of LDS col 0
    const int cshift  = (tp == 1) ? 6 : 5;      // log2(C/4)
    const int cmask   = (C >> 2) - 1;
    const int nunits  = C >> 7;                 // 1 or 2
    const int bcol    = (tp == 1) ? 128 : 0;    // B-operand base col in LDS

    __shared__ bf16_t lds[256 * KSTRIDE];       // [col][k], transposed tile

    const float* xb = x + (size_t)b * NL * ND;
    const float* sb = ws + WS_S_OFF + b * NL;
    const int l0 = ks * (NL / KSPLIT);

    floatx4 acc[2][8];
    #pragma unroll
    for (int rt = 0; rt < 2; ++rt)
        #pragma unroll
        for (int ct = 0; ct < 8; ++ct)
            #pragma unroll
            for (int r = 0; r < 4; ++r) acc[rt][ct][r] = 0.f;

    for (int kk = 0; kk < NL / KSPLIT; kk += BK) {
        __syncthreads();
        // stage: unit = 4 cols x 8 k's: 8 float4 loads (16B/lane coalesced),
        // scale by s, pack transposed, 4x ds_write_b128.
        for (int i = 0; i < nunits; ++i) {
            const int u  = t + i * 256;
            const int cg = u & cmask;
            const int kg = u >> cshift;         // 0..7
            const int lrow = l0 + kk + kg * 8;
            const float* gp = xb + (size_t)lrow * ND + col_off + cg * 4;
            bf16x8 p[4];
            {
                float4 v[4]; float sc[4];
                #pragma unroll
                for (int j = 0; j < 4; ++j) { v[j] = *(const float4*)(gp + j * ND); sc[j] = sb[lrow + j]; }
                #pragma unroll
                for (int c = 0; c < 4; ++c) {
                    const float* vf;
                    #pragma unroll
                    for (int j = 0; j < 4; ++j) { vf = (const float*)&v[j]; p[c][j] = (bf16_t)(vf[c] * sc[j]); }
                }
            }
            {
                float4 v[4]; float sc[4];
                #pragma unroll
                for (int j = 0; j < 4; ++j) { v[j] = *(const float4*)(gp + (j + 4) * ND); sc[j] = sb[lrow + 4 + j]; }
                #pragma unroll
                for (int c = 0; c < 4; ++c) {
                    const float* vf;
                    #pragma unroll
                    for (int j = 0; j < 4; ++j) { vf = (const float*)&v[j]; p[c][4 + j] = (bf16_t)(vf[c] * sc[j]); }
                }
            }
            #pragma unroll
            for (int c = 0; c < 4; ++c)
                *(bf16x8*)(lds + (4 * cg + c) * KSTRIDE + kg * 8) = p[c];
        }
        __syncthreads();
        #pragma unroll
        for (int k2 = 0; k2 < 2; ++k2) {
            const int koff = k2 * 32 + (lane >> 4) * 8;
            bf16x8 af[2], bfr[8];
            #pragma unroll
            for (int rt = 0; rt < 2; ++rt) {
                const int col = (wave * 2 + rt) * 16 + (lane & 15);
                af[rt] = *(const bf16x8*)(lds + col * KSTRIDE + koff);
            }
            #pragma unroll
            for (int ct = 0; ct < 8; ++ct) {
                const int col = bcol + ct * 16 + (lane & 15);
                bfr[ct] = *(const bf16x8*)(lds + col * KSTRIDE + koff);
            }
            #pragma unroll
            for (int rt = 0; rt < 2; ++rt)
                #pragma unroll
                for (int ct = 0; ct < 8; ++ct)
                    acc[rt][ct] = __builtin_amdgcn_mfma_f32_16x16x32_bf16(
                        af[rt], bfr[ct], acc[rt][ct], 0, 0, 0);
        }
    }

    // epilogue: plain stores of the 128x128 partial (C/D: col=lane&15, row=(lane>>4)*4+reg)
    float* wq = gram + (size_t)((ks * 3 + tp) * 16 + b) * 16384;
    #pragma unroll
    for (int rt = 0; rt < 2; ++rt) {
        const int d0 = (wave * 2 + rt) * 16 + (lane >> 4) * 4;
        #pragma unroll
        for (int ct = 0; ct < 8; ++ct) {
            const int e = ct * 16 + (lane & 15);
            #pragma unroll
            for (int reg = 0; reg < 4; ++reg)
                wq[(size_t)(d0 + reg) * 128 + e] = acc[rt][ct][reg];
        }
    }
}

// K4: sum KSPLIT partials, scale by rz = ws[b], scatter 3 quadrants to out.
__global__ __launch_bounds__(256) void k_reduce(const float* __restrict__ gram,
                                                const float* __restrict__ ws,
                                                float* __restrict__ out) {
    const int gid = blockIdx.x * 256 + threadIdx.x;
    const int idx = gid & 16383;
    const int q   = gid >> 14;        // 0..47
    const int tp  = q / 16;
    const int b   = q % 16;
    const float rz = ws[b];
    float sum = 0.f;
    #pragma unroll
    for (int ks = 0; ks < KSPLIT; ++ks)
        sum += gram[(size_t)((ks * 3 + tp) * 16 + b) * 16384 + idx];
    sum *= rz;
    const int d = idx >> 7, e = idx & 127;
    float* ob = out + (size_t)b * ND * ND;
    if (tp == 0)      ob[(size_t)d * ND + e] = sum;
    else if (tp == 1) ob[(size_t)d * ND + 128 + e] = sum;
    else              ob[(size_t)(128 + d) * ND + 128 + e] = sum;
}

// K5: out[b, 128:, :128] = out[b, :128, 128:]^T via LDS 32x32 tiles.
__global__ __launch_bounds__(256) void k_mirror(float* __restrict__ out) {
    __shared__ float tile[32][33];
    const int tx = threadIdx.x & 31, ty = threadIdx.x >> 5;   // 32x8
    const int x0 = blockIdx.x * 32;   // d
    const int y0 = blockIdx.y * 32;   // e-local
    float* ob = out + (size_t)blockIdx.z * ND * ND;
    #pragma unroll
    for (int p = 0; p < 4; ++p)
        tile[ty + 8 * p][tx] = ob[(size_t)(x0 + ty + 8 * p) * ND + 128 + y0 + tx];
    __syncthreads();
    #pragma unroll
    for (int p = 0; p < 4; ++p)
        ob[(size_t)(128 + y0 + ty + 8 * p) * ND + x0 + tx] = tile[tx][ty + 8 * p];
}

extern "C" void kernel_launch(void* const* d_in, const int* in_sizes, int n_in,
                              void* d_out, int out_size, void* d_ws, size_t ws_size,
                              hipStream_t stream) {
    const float* x = (const float*)d_in[0];
    float* out = (float*)d_out;
    float* ws = (float*)d_ws;
    float* gram = ws + WS_G_OFF;

    k_norm_exp<<<dim3(NB * NL / 64), 256, 0, stream>>>(x, ws);
    k_zsum<<<dim3(NB), 256, 0, stream>>>(ws);
    k_gemm<<<dim3(KSPLIT, 3, NB), 256, 0, stream>>>(x, ws, gram);
    k_reduce<<<dim3(3 * NB * 16384 / 256), 256, 0, stream>>>(gram, ws, out);
    k_mirror<<<dim3(4, 4, NB), 256, 0, stream>>>(out);
}

// Round 5
// 253.527 us; speedup vs baseline: 1.0959x; 1.0213x over previous
//
#include <hip/hip_runtime.h>
#include <hip/hip_bf16.h>

#define NB 16
#define NL 8192
#define ND 256

#define KSPLIT 32
#define BK 64
#define KSTRIDE 72   // bf16 elems per LDS column; 144 B -> 16B aligned

// ws layout (floats): Z[b] at ws[b*16] (64B-spaced); gram partials at WS_G_OFF
#define WS_G_OFF 131328

typedef __bf16 bf16_t;
typedef __attribute__((ext_vector_type(8))) __bf16 bf16x8;
typedef __attribute__((ext_vector_type(4))) float floatx4;

// K3: per batch, partial Gram of Y = diag(s) X over a k-chunk, bf16 MFMA,
// with s_l = exp(|x_l|/2) computed ON THE FLY during staging (norm is
// row-local; wave-level butterfly over the 64 col-group lanes, s broadcast).
// blockIdx: x = k-chunk, y = quadrant tp {0:(0,0), 1:(0,1), 2:(1,1)}, z = batch.
// All tps stage the full 256-col row. tp==0 blocks also accumulate
// Z_b = sum(exp|x_l|) via one atomicAdd per block into ws[b*16].
__global__ __launch_bounds__(256, 4) void k_gemm(const float* __restrict__ x,
                                                 float* __restrict__ ws,
                                                 float* __restrict__ gram) {
    const int ks = blockIdx.x;
    const int tp = blockIdx.y;
    const int b  = blockIdx.z;
    const int t = threadIdx.x;
    const int wave = t >> 6, lane = t & 63;

    const int acolb = (tp == 2) ? 128 : 0;   // A-operand base col in LDS
    const int bcolb = (tp == 0) ? 0 : 128;   // B-operand base col in LDS

    __shared__ bf16_t lds[256 * KSTRIDE];    // [col][k], transposed tile

    const float* xb = x + (size_t)b * NL * ND;
    const int l0 = ks * (NL / KSPLIT);

    floatx4 acc[2][8];
    #pragma unroll
    for (int rt = 0; rt < 2; ++rt)
        #pragma unroll
        for (int ct = 0; ct < 8; ++ct)
            #pragma unroll
            for (int r = 0; r < 4; ++r) acc[rt][ct][r] = 0.f;

    float e_acc = 0.f;   // wave-uniform partial of Z (rows this wave staged)

    for (int kk = 0; kk < NL / KSPLIT; kk += BK) {
        __syncthreads();
        // stage: unit u covers 4 cols (cg) x 8 rows (kg). Within a unit the
        // 64 lanes of a wave hold the full 256 cols of the same 8 rows
        // (u = t + 256i -> cg = lane, kg = wave + 4i), so a wave butterfly
        // over lanes yields the row sum-of-squares, broadcast to all lanes.
        #pragma unroll
        for (int i = 0; i < 2; ++i) {
            const int u  = t + i * 256;
            const int cg = u & 63;
            const int kg = u >> 6;              // == wave + 4*i
            const int lrow = l0 + kk + kg * 8;
            const float* gp = xb + (size_t)lrow * ND + cg * 4;
            bf16x8 p[4];
            #pragma unroll
            for (int h = 0; h < 2; ++h) {       // two 4-row halves
                float4 v[4]; float ss[4];
                #pragma unroll
                for (int j = 0; j < 4; ++j) {
                    v[j] = *(const float4*)(gp + (size_t)(h * 4 + j) * ND);
                    ss[j] = v[j].x * v[j].x + v[j].y * v[j].y
                          + v[j].z * v[j].z + v[j].w * v[j].w;
                }
                #pragma unroll
                for (int off = 32; off; off >>= 1) {
                    #pragma unroll
                    for (int j = 0; j < 4; ++j) ss[j] += __shfl_xor(ss[j], off, 64);
                }
                #pragma unroll
                for (int j = 0; j < 4; ++j) {
                    const float s = __expf(0.5f * sqrtf(ss[j]));  // sqrt(e_l)
                    e_acc += s * s;
                    const float* vf = (const float*)&v[j];
                    #pragma unroll
                    for (int c = 0; c < 4; ++c)
                        p[c][h * 4 + j] = (bf16_t)(vf[c] * s);
                }
            }
            #pragma unroll
            for (int c = 0; c < 4; ++c)
                *(bf16x8*)(lds + (4 * cg + c) * KSTRIDE + kg * 8) = p[c];
        }
        __syncthreads();
        #pragma unroll
        for (int k2 = 0; k2 < 2; ++k2) {
            const int koff = k2 * 32 + (lane >> 4) * 8;
            bf16x8 af[2], bfr[8];
            #pragma unroll
            for (int rt = 0; rt < 2; ++rt) {
                const int col = acolb + (wave * 2 + rt) * 16 + (lane & 15);
                af[rt] = *(const bf16x8*)(lds + col * KSTRIDE + koff);
            }
            #pragma unroll
            for (int ct = 0; ct < 8; ++ct) {
                const int col = bcolb + ct * 16 + (lane & 15);
                bfr[ct] = *(const bf16x8*)(lds + col * KSTRIDE + koff);
            }
            #pragma unroll
            for (int rt = 0; rt < 2; ++rt)
                #pragma unroll
                for (int ct = 0; ct < 8; ++ct)
                    acc[rt][ct] = __builtin_amdgcn_mfma_f32_16x16x32_bf16(
                        af[rt], bfr[ct], acc[rt][ct], 0, 0, 0);
        }
    }

    // Z accumulation: e_acc is lane-uniform per wave; rows covered once per
    // (b,ks) by tp==0 blocks only. Padded slots -> no cacheline contention.
    if (tp == 0) {
        __shared__ float red[4];
        if (lane == 0) red[wave] = e_acc;
        __syncthreads();
        if (t == 0) atomicAdd(&ws[b * 16], red[0] + red[1] + red[2] + red[3]);
    }

    // epilogue: plain stores of the 128x128 partial (C/D: col=lane&15, row=(lane>>4)*4+reg)
    float* wq = gram + (size_t)((ks * 3 + tp) * 16 + b) * 16384;
    #pragma unroll
    for (int rt = 0; rt < 2; ++rt) {
        const int d0 = (wave * 2 + rt) * 16 + (lane >> 4) * 4;
        #pragma unroll
        for (int ct = 0; ct < 8; ++ct) {
            const int e = ct * 16 + (lane & 15);
            #pragma unroll
            for (int reg = 0; reg < 4; ++reg)
                wq[(size_t)(d0 + reg) * 128 + e] = acc[rt][ct][reg];
        }
    }
}

// K4: sum KSPLIT partials, scale by 1/Z, scatter quadrants to out.
// tp==1 also writes the mirrored (1,0) quadrant (transposed scatter).
__global__ __launch_bounds__(256) void k_reduce(const float* __restrict__ gram,
                                                const float* __restrict__ ws,
                                                float* __restrict__ out) {
    const int gid = blockIdx.x * 256 + threadIdx.x;
    const int idx = gid & 16383;
    const int q   = gid >> 14;        // 0..47
    const int tp  = q / 16;
    const int b   = q % 16;
    const float rz = 1.0f / ws[b * 16];
    float sum = 0.f;
    #pragma unroll
    for (int ks = 0; ks < KSPLIT; ++ks)
        sum += gram[(size_t)((ks * 3 + tp) * 16 + b) * 16384 + idx];
    sum *= rz;
    const int d = idx >> 7, e = idx & 127;
    float* ob = out + (size_t)b * ND * ND;
    if (tp == 0) {
        ob[(size_t)d * ND + e] = sum;
    } else if (tp == 2) {
        ob[(size_t)(128 + d) * ND + 128 + e] = sum;
    } else {
        ob[(size_t)d * ND + 128 + e] = sum;
        ob[(size_t)(128 + e) * ND + d] = sum;   // mirror (1,0)
    }
}

extern "C" void kernel_launch(void* const* d_in, const int* in_sizes, int n_in,
                              void* d_out, int out_size, void* d_ws, size_t ws_size,
                              hipStream_t stream) {
    const float* x = (const float*)d_in[0];
    float* out = (float*)d_out;
    float* ws = (float*)d_ws;
    float* gram = ws + WS_G_OFF;

    hipMemsetAsync(d_ws, 0, 1024, stream);  // zero Z slots ws[0..256)
    k_gemm<<<dim3(KSPLIT, 3, NB), 256, 0, stream>>>(x, ws, gram);
    k_reduce<<<dim3(3 * NB * 16384 / 256), 256, 0, stream>>>(gram, ws, out);
}

// Round 6
// 207.721 us; speedup vs baseline: 1.3376x; 1.2205x over previous
//
#include <hip/hip_runtime.h>
#include <hip/hip_bf16.h>

#define NB 16
#define NL 8192
#define ND 256
#define KSPLIT 16
#define CHUNK (NL / KSPLIT)   // 512 rows per block
#define BK 64

#define WS_G_OFF 256          // floats; Z[b] lives at ws[b*16] (64B-spaced)

typedef __bf16 bf16_t;
typedef __attribute__((ext_vector_type(8))) __bf16 bf16x8;
typedef __attribute__((ext_vector_type(4))) float floatx4;

// LDS layout: per col (0..255), 8 chunks of 8 bf16 (16B). Physical chunk =
// kg ^ fsw(col). Algebra: writes (col=4*lane+c) spread lanes via lane&7;
// reads (col=ct*16+m) spread via (m>>2)^((m&3)<<1) + parity(ct) -> both
// uniform 8 lanes / 4-bank position = b128 minimum cost.
__device__ __forceinline__ int fsw(int col) {
    return ((col >> 2) & 7) ^ ((col & 3) << 1);
}

// One block = 512 threads = 8 waves, one (ks, b) chunk of 512 rows.
// Wave w computes output row-tiles {w, w+8} x col-tiles (rt+j)&15 (circulant):
// row w: j=0..8, row w+8: j=0..7  -> 17 tiles/wave, 136 total = exact upper-tri.
// s_l = exp(|x_l|/2) computed in staging via wave butterfly (rows staged once).
__global__ __launch_bounds__(512, 2) void k_gemm(const float* __restrict__ x,
                                                 float* __restrict__ ws,
                                                 float* __restrict__ gram) {
    const int ks = blockIdx.x, b = blockIdx.y;
    const int t = threadIdx.x;
    const int lane = t & 63;
    const int w = __builtin_amdgcn_readfirstlane(t >> 6);   // wave id 0..7
    const int quad = lane >> 4, m = lane & 15;

    __shared__ bf16_t lds[256 * 64];   // 32 KB, swizzled

    const float* xb = x + (size_t)b * NL * ND;
    const int l0 = ks * CHUNK;

    floatx4 accA[9], accB[8];
    #pragma unroll
    for (int j = 0; j < 9; ++j)
        #pragma unroll
        for (int r = 0; r < 4; ++r) accA[j][r] = 0.f;
    #pragma unroll
    for (int j = 0; j < 8; ++j)
        #pragma unroll
        for (int r = 0; r < 4; ++r) accB[j][r] = 0.f;

    float e_acc = 0.f;
    float4 xv[8];   // prefetch regs: 8 rows x 4 cols (lane*4..+3)

    // unit: wave w stages rows l0+kk+w*8 .. +7, lane covers cols lane*4..+3
    {
        const float* gp = xb + (size_t)(l0 + w * 8) * ND + lane * 4;
        #pragma unroll
        for (int j = 0; j < 8; ++j) xv[j] = *(const float4*)(gp + (size_t)j * ND);
    }

    for (int kk = 0; kk < CHUNK; kk += BK) {
        if (kk) __syncthreads();   // prev iter's LDS reads done
        // ---- convert + swizzled LDS write ----
        {
            float ss[8];
            #pragma unroll
            for (int j = 0; j < 8; ++j)
                ss[j] = xv[j].x * xv[j].x + xv[j].y * xv[j].y
                      + xv[j].z * xv[j].z + xv[j].w * xv[j].w;
            #pragma unroll
            for (int off = 32; off; off >>= 1) {
                #pragma unroll
                for (int j = 0; j < 8; ++j) ss[j] += __shfl_xor(ss[j], off, 64);
            }
            float s[8];
            #pragma unroll
            for (int j = 0; j < 8; ++j) {
                s[j] = __expf(0.5f * sqrtf(ss[j]));   // sqrt of softmax numerator
                e_acc += s[j] * s[j];
            }
            bf16x8 p[4];
            #pragma unroll
            for (int j = 0; j < 8; ++j) {
                const float* vf = (const float*)&xv[j];
                #pragma unroll
                for (int c = 0; c < 4; ++c) p[c][j] = (bf16_t)(vf[c] * s[j]);
            }
            #pragma unroll
            for (int c = 0; c < 4; ++c) {
                const int col = 4 * lane + c;
                const int chunk = w ^ fsw(col);
                *(bf16x8*)(&lds[col * 64 + chunk * 8]) = p[c];
            }
        }
        __syncthreads();
        // ---- prefetch next iter (lands during MFMA below) ----
        if (kk + BK < CHUNK) {
            const float* gp = xb + (size_t)(l0 + kk + BK + w * 8) * ND + lane * 4;
            #pragma unroll
            for (int j = 0; j < 8; ++j) xv[j] = *(const float4*)(gp + (size_t)j * ND);
        }
        // ---- MFMA: 16 reads, 17 MFMAs per k-step ----
        #pragma unroll
        for (int k2 = 0; k2 < 2; ++k2) {
            const int kcq = k2 * 4 + quad;
            bf16x8 fB[16];
            #pragma unroll
            for (int j = 0; j < 16; ++j) {
                const int col = (((w + j) & 15) << 4) + m;
                fB[j] = *(const bf16x8*)(&lds[(col << 6) + ((kcq ^ fsw(col)) << 3)]);
            }
            #pragma unroll
            for (int j = 0; j < 9; ++j)
                accA[j] = __builtin_amdgcn_mfma_f32_16x16x32_bf16(fB[0], fB[j], accA[j], 0, 0, 0);
            #pragma unroll
            for (int j = 0; j < 8; ++j)
                accB[j] = __builtin_amdgcn_mfma_f32_16x16x32_bf16(fB[8], fB[8 + j], accB[j], 0, 0, 0);
        }
    }

    // ---- Z accumulation: one padded atomic per block ----
    __shared__ float red[8];
    if (lane == 0) red[w] = e_acc;
    __syncthreads();
    if (t == 0) {
        float z = 0.f;
        #pragma unroll
        for (int i = 0; i < 8; ++i) z += red[i];
        atomicAdd(&ws[b * 16], z);
    }

    // ---- epilogue: 17 tiles -> gram[ks][b][slot][256], slot = rt*9 + j ----
    float* gb = gram + (size_t)(ks * NB + b) * 144 * 256;
    #pragma unroll
    for (int j = 0; j < 9; ++j) {
        float* tb = gb + (w * 9 + j) * 256 + quad * 64 + m;
        #pragma unroll
        for (int reg = 0; reg < 4; ++reg) tb[reg * 16] = accA[j][reg];
    }
    #pragma unroll
    for (int j = 0; j < 8; ++j) {
        float* tb = gb + ((w + 8) * 9 + j) * 256 + quad * 64 + m;
        #pragma unroll
        for (int reg = 0; reg < 4; ++reg) tb[reg * 16] = accB[j][reg];
    }
}

// Sum KSPLIT partials, scale by 1/Z, scatter tile (rt, ct=(rt+j)&15) + mirror.
__global__ __launch_bounds__(256) void k_reduce(const float* __restrict__ gram,
                                                const float* __restrict__ ws,
                                                float* __restrict__ out) {
    const int gid = blockIdx.x * 256 + threadIdx.x;
    const int elem = gid & 255;
    const int rem  = gid >> 8;          // b*144 + slot
    const int slot = rem % 144;
    const int b    = rem / 144;
    const int rt = slot / 9;
    const int j  = slot - rt * 9;
    if (rt >= 8 && j == 8) return;      // unwritten pad slot (uniform per block)
    const int ct = (rt + j) & 15;
    float sum = 0.f;
    #pragma unroll
    for (int ks = 0; ks < KSPLIT; ++ks)
        sum += gram[((size_t)(ks * NB + b) * 144 + slot) * 256 + elem];
    sum *= 1.0f / ws[b * 16];
    const int er = elem >> 4, ec = elem & 15;
    const int d = rt * 16 + er, e = ct * 16 + ec;
    float* ob = out + (size_t)b * ND * ND;
    ob[(size_t)d * ND + e] = sum;
    if (j) ob[(size_t)e * ND + d] = sum;   // mirror (lower triangle)
}

extern "C" void kernel_launch(void* const* d_in, const int* in_sizes, int n_in,
                              void* d_out, int out_size, void* d_ws, size_t ws_size,
                              hipStream_t stream) {
    const float* x = (const float*)d_in[0];
    float* out = (float*)d_out;
    float* ws = (float*)d_ws;
    float* gram = ws + WS_G_OFF;

    hipMemsetAsync(d_ws, 0, 1024, stream);  // zero Z slots
    k_gemm<<<dim3(KSPLIT, NB), 512, 0, stream>>>(x, ws, gram);
    k_reduce<<<dim3(NB * 144 * 256 / 256), 256, 0, stream>>>(gram, ws, out);
}

// Round 7
// 207.240 us; speedup vs baseline: 1.3407x; 1.0023x over previous
//
#include <hip/hip_runtime.h>
#include <hip/hip_bf16.h>

#define NB 16
#define NL 8192
#define ND 256
#define KSPLIT 16
#define CHUNK (NL / KSPLIT)   // 512 rows per block
#define BK 64

#define WS_G_OFF 256          // floats; Z[b] lives at ws[b*16] (64B-spaced)

typedef __bf16 bf16_t;
typedef __attribute__((ext_vector_type(4))) __bf16 bf16x4;
typedef __attribute__((ext_vector_type(8))) __bf16 bf16x8;
typedef __attribute__((ext_vector_type(4))) float floatx4;

// LDS: per col (0..255), 8 chunks of 8 bf16 (16B); physical chunk = kg ^ fsw(col).
__device__ __forceinline__ int fsw(int col) {
    return ((col >> 2) & 7) ^ ((col & 3) << 1);
}

// One block = 1024 threads = 16 waves, one (ks,b) chunk of 512 rows.
// Wave w computes row-tile w x col-tiles (w+j)&15, j=0..8 -> 144 slots
// (136 unique upper-tri + 8 d=8 pairs written once each side, no overlap).
// acc = 9 x floatx4 = 36 VGPRs -> fits 128-cap -> 4 waves/SIMD.
__global__ __launch_bounds__(1024, 4) void k_gemm(const float* __restrict__ x,
                                                  float* __restrict__ ws,
                                                  float* __restrict__ gram) {
    const int ks = blockIdx.x, b = blockIdx.y;
    const int t = threadIdx.x;
    const int lane = t & 63;
    const int w = __builtin_amdgcn_readfirstlane(t >> 6);   // wave id 0..15
    const int quad = lane >> 4, m = lane & 15;
    const int g = w >> 1, h = w & 1;   // 8-row chunk id, half within chunk

    __shared__ bf16_t lds[256 * 64];   // 32 KB, swizzled

    const float* xb = x + (size_t)b * NL * ND;
    const int l0 = ks * CHUNK;

    floatx4 acc[9];
    #pragma unroll
    for (int j = 0; j < 9; ++j)
        #pragma unroll
        for (int r = 0; r < 4; ++r) acc[j][r] = 0.f;

    float e_acc = 0.f;
    float4 xv[4];   // wave w stages rows l0+kk+4w .. +3; lane covers cols 4*lane..+3
    {
        const float* gp = xb + (size_t)(l0 + w * 4) * ND + lane * 4;
        #pragma unroll
        for (int j = 0; j < 4; ++j) xv[j] = *(const float4*)(gp + (size_t)j * ND);
    }

    for (int kk = 0; kk < CHUNK; kk += BK) {
        if (kk) __syncthreads();   // prev iter's LDS reads done
        // ---- norm butterfly + scale + swizzled LDS write (bf16x4 half-chunk) ----
        {
            float ss[4];
            #pragma unroll
            for (int j = 0; j < 4; ++j)
                ss[j] = xv[j].x * xv[j].x + xv[j].y * xv[j].y
                      + xv[j].z * xv[j].z + xv[j].w * xv[j].w;
            #pragma unroll
            for (int off = 32; off; off >>= 1) {
                #pragma unroll
                for (int j = 0; j < 4; ++j) ss[j] += __shfl_xor(ss[j], off, 64);
            }
            float s[4];
            #pragma unroll
            for (int j = 0; j < 4; ++j) {
                s[j] = __expf(0.5f * sqrtf(ss[j]));   // sqrt of softmax numerator
                e_acc += s[j] * s[j];
            }
            bf16x4 p[4];
            #pragma unroll
            for (int j = 0; j < 4; ++j) {
                const float* vf = (const float*)&xv[j];
                #pragma unroll
                for (int c = 0; c < 4; ++c) p[c][j] = (bf16_t)(vf[c] * s[j]);
            }
            #pragma unroll
            for (int c = 0; c < 4; ++c) {
                const int col = 4 * lane + c;
                *(bf16x4*)(&lds[col * 64 + ((g ^ fsw(col)) << 3) + (h << 2)]) = p[c];
            }
        }
        __syncthreads();
        // ---- prefetch next iter (lands during MFMA below) ----
        if (kk + BK < CHUNK) {
            const float* gp = xb + (size_t)(l0 + kk + BK + w * 4) * ND + lane * 4;
            #pragma unroll
            for (int j = 0; j < 4; ++j) xv[j] = *(const float4*)(gp + (size_t)j * ND);
        }
        // ---- MFMA: frag0 reused as A; 9 streamed B-frags per k2 ----
        #pragma unroll
        for (int k2 = 0; k2 < 2; ++k2) {
            const int kcq = k2 * 4 + quad;
            const int col0 = (w << 4) + m;
            const bf16x8 f0 = *(const bf16x8*)(&lds[(col0 << 6) + ((kcq ^ fsw(col0)) << 3)]);
            #pragma unroll
            for (int j = 0; j < 9; ++j) {
                const int col = (((w + j) & 15) << 4) + m;
                const bf16x8 fj = *(const bf16x8*)(&lds[(col << 6) + ((kcq ^ fsw(col)) << 3)]);
                acc[j] = __builtin_amdgcn_mfma_f32_16x16x32_bf16(f0, fj, acc[j], 0, 0, 0);
            }
        }
    }

    // ---- Z accumulation: one padded atomic per block ----
    __shared__ float red[16];
    if (lane == 0) red[w] = e_acc;
    __syncthreads();
    if (t == 0) {
        float z = 0.f;
        #pragma unroll
        for (int i = 0; i < 16; ++i) z += red[i];
        atomicAdd(&ws[b * 16], z);
    }

    // ---- epilogue: 9 tiles -> gram[ks][b][slot=w*9+j][256] ----
    float* gb = gram + (size_t)(ks * NB + b) * 144 * 256;
    #pragma unroll
    for (int j = 0; j < 9; ++j) {
        float* tb = gb + (w * 9 + j) * 256 + quad * 64 + m;
        #pragma unroll
        for (int reg = 0; reg < 4; ++reg) tb[reg * 16] = acc[j][reg];
    }
}

// Sum KSPLIT partials, scale by 1/Z, scatter tile (rt=w, ct=(w+j)&15).
// Mirror only j=1..7 (j=0 diagonal; j=8 pairs each written directly once).
__global__ __launch_bounds__(256) void k_reduce(const float* __restrict__ gram,
                                                const float* __restrict__ ws,
                                                float* __restrict__ out) {
    const int gid = blockIdx.x * 256 + threadIdx.x;
    const int elem = gid & 255;
    const int rem  = gid >> 8;          // b*144 + slot
    const int slot = rem % 144;
    const int b    = rem / 144;
    const int rt = slot / 9;
    const int j  = slot - rt * 9;
    const int ct = (rt + j) & 15;
    float sum = 0.f;
    #pragma unroll
    for (int ks = 0; ks < KSPLIT; ++ks)
        sum += gram[((size_t)(ks * NB + b) * 144 + slot) * 256 + elem];
    sum *= 1.0f / ws[b * 16];
    const int er = elem >> 4, ec = elem & 15;
    const int d = rt * 16 + er, e = ct * 16 + ec;
    float* ob = out + (size_t)b * ND * ND;
    ob[(size_t)d * ND + e] = sum;
    if (j >= 1 && j <= 7) ob[(size_t)e * ND + d] = sum;   // mirror
}

extern "C" void kernel_launch(void* const* d_in, const int* in_sizes, int n_in,
                              void* d_out, int out_size, void* d_ws, size_t ws_size,
                              hipStream_t stream) {
    const float* x = (const float*)d_in[0];
    float* out = (float*)d_out;
    float* ws = (float*)d_ws;
    float* gram = ws + WS_G_OFF;

    hipMemsetAsync(d_ws, 0, 1024, stream);  // zero Z slots
    k_gemm<<<dim3(KSPLIT, NB), 1024, 0, stream>>>(x, ws, gram);
    k_reduce<<<dim3(NB * 144 * 256 / 256), 256, 0, stream>>>(gram, ws, out);
}